// Round 7
// baseline (202.047 us; speedup 1.0000x reference)
//
#include <hip/hip_runtime.h>
#include <hip/hip_bf16.h>

// Chamfer loss: preds/gts [8, 3, 8192] fp32 -> scalar fp32.
//
// Phase 0 (pack): refs+queries packed as (y0,y1,y2,-0.5*|y|^2) float4;
//                 also zeroes the accumulator + ticket counter.
// Phase 1 (partial): per-query max_j(dot - 0.5*ry) over a ref split.
//                 Refs read at wave-UNIFORM addresses -> scalar/broadcast
//                 loads; no LDS, no barriers. Inner loop = 3 fma + 0.5 v_max3
//                 per pair (inline asm; clang won't fuse fmaxf w/o fast-math).
// Phase 2 (reduce): min over splits, block sum, double atomic add; last
//                 block (atomic ticket) writes the float output.

#define CN 8192
#define NBATCH 8
#define BQ 2048        // queries per block
#define IPT 8          // queries per thread (256 threads * 8)
#define SPLITS 8       // ref-range splits
#define RB (CN / SPLITS)   // 1024 refs per block
#define QCHUNKS (CN / BQ)  // 4

__global__ __launch_bounds__(256) void chamfer_pack(
    const float* __restrict__ preds, const float* __restrict__ gts,
    float4* __restrict__ ppack, float4* __restrict__ gpack,
    double* __restrict__ acc, unsigned* __restrict__ cnt) {
  const int g = blockIdx.x * 256 + threadIdx.x;  // 65536 = 8*8192
  if (g == 0) { *acc = 0.0; *cnt = 0u; }
  const int batch = g >> 13, i = g & (CN - 1);
  const float* __restrict__ P = preds + batch * 3 * CN;
  const float p0 = P[i], p1 = P[CN + i], p2 = P[2 * CN + i];
  ppack[g] =
      make_float4(p0, p1, p2, -0.5f * fmaf(p0, p0, fmaf(p1, p1, p2 * p2)));
  const float* __restrict__ G = gts + batch * 3 * CN;
  const float g0 = G[i], g1 = G[CN + i], g2 = G[2 * CN + i];
  gpack[g] =
      make_float4(g0, g1, g2, -0.5f * fmaf(g0, g0, fmaf(g1, g1, g2 * g2)));
}

__global__ __launch_bounds__(256) void chamfer_partial(
    const float4* __restrict__ ppack, const float4* __restrict__ gpack,
    float* __restrict__ partial) {
  const int bid = blockIdx.x;            // 512 blocks
  const int s     = bid & (SPLITS - 1);
  const int qc    = (bid >> 3) & (QCHUNKS - 1);
  const int batch = (bid >> 5) & (NBATCH - 1);
  const int dir   = bid >> 8;            // 0: queries=preds, 1: queries=gts

  const float4* __restrict__ Qp = (dir ? gpack : ppack) + batch * CN;
  const float4* __restrict__ Rp = (dir ? ppack : gpack) + batch * CN + s * RB;
  const int tid = threadIdx.x;

  float x0[IPT], x1[IPT], x2[IPT], xw[IPT], mm[IPT];
#pragma unroll
  for (int k = 0; k < IPT; ++k) {
    const float4 v = Qp[qc * BQ + k * 256 + tid];  // coalesced float4
    x0[k] = v.x; x1[k] = v.y; x2[k] = v.z; xw[k] = v.w;
    mm[k] = -INFINITY;   // tracks max_j (dot - 0.5*ry)
  }

  for (int j = 0; j < RB; j += 4) {
    // Wave-uniform addresses -> scalar/broadcast loads, off the VALU pipe.
    const float4 ya = Rp[j];
    const float4 yb = Rp[j + 1];
    const float4 yc = Rp[j + 2];
    const float4 yd = Rp[j + 3];
#pragma unroll
    for (int k = 0; k < IPT; ++k) {
      const float ta =
          fmaf(x2[k], ya.z, fmaf(x1[k], ya.y, fmaf(x0[k], ya.x, ya.w)));
      const float tb =
          fmaf(x2[k], yb.z, fmaf(x1[k], yb.y, fmaf(x0[k], yb.x, yb.w)));
      const float tc =
          fmaf(x2[k], yc.z, fmaf(x1[k], yc.y, fmaf(x0[k], yc.x, yc.w)));
      const float td =
          fmaf(x2[k], yd.z, fmaf(x1[k], yd.y, fmaf(x0[k], yd.x, yd.w)));
      asm("v_max3_f32 %0, %0, %1, %2" : "+v"(mm[k]) : "v"(ta), "v"(tb));
      asm("v_max3_f32 %0, %0, %1, %2" : "+v"(mm[k]) : "v"(tc), "v"(td));
    }
  }

  // partial = rx + min_j(ry - 2dot) = -2*xw - 2*mm = -2*(xw + mm)
  float* __restrict__ P =
      partial +
      (size_t)(((dir * NBATCH + batch) * QCHUNKS + qc) * SPLITS + s) * BQ;
#pragma unroll
  for (int k = 0; k < IPT; ++k) P[k * 256 + tid] = -2.0f * (xw[k] + mm[k]);
}

__global__ __launch_bounds__(256) void chamfer_reduce(
    const float* __restrict__ partial, double* __restrict__ acc,
    unsigned* __restrict__ cnt, float* __restrict__ out) {
  const int tid = threadIdx.x;
  const int g = blockIdx.x * 256 + tid;   // 131072 queries
  const int qlocal = g & (BQ - 1);
  const int grp = g >> 11;                // (dir*8+batch)*QCHUNKS+qc

  const float* __restrict__ P = partial + (size_t)grp * (SPLITS * BQ) + qlocal;
  float m = P[0];
#pragma unroll
  for (int s2 = 1; s2 < SPLITS; ++s2) m = fminf(m, P[s2 * BQ]);

  float v = m;
#pragma unroll
  for (int off = 32; off > 0; off >>= 1) v += __shfl_down(v, off, 64);

  __shared__ float wsum[4];
  if ((tid & 63) == 0) wsum[tid >> 6] = v;
  __syncthreads();
  if (tid == 0) {
    atomicAdd(acc, (double)(wsum[0] + wsum[1] + wsum[2] + wsum[3]));
    __threadfence();
    const unsigned t = atomicAdd(cnt, 1u);
    if (t == gridDim.x - 1) {
      // All prior adds are ordered before their ticket increments; we hold
      // the last ticket, so this atomic read returns the full sum.
      const double total = atomicAdd(acc, 0.0);
      out[0] = (float)total;
    }
  }
}

extern "C" void kernel_launch(void* const* d_in, const int* in_sizes, int n_in,
                              void* d_out, int out_size, void* d_ws, size_t ws_size,
                              hipStream_t stream) {
  const float* preds = (const float*)d_in[0];
  const float* gts   = (const float*)d_in[1];

  double*   acc     = (double*)d_ws;
  unsigned* cnt     = (unsigned*)((char*)d_ws + 8);
  float4*   ppack   = (float4*)((char*)d_ws + 256);
  float4*   gpack   = (float4*)((char*)d_ws + 256 + (size_t)NBATCH * CN * 16);
  float*    partial = (float*)((char*)d_ws + 256 + (size_t)2 * NBATCH * CN * 16);

  chamfer_pack<<<256, 256, 0, stream>>>(preds, gts, ppack, gpack, acc, cnt);
  chamfer_partial<<<512, 256, 0, stream>>>(ppack, gpack, partial);
  chamfer_reduce<<<512, 256, 0, stream>>>(partial, acc, cnt, (float*)d_out);
}

// Round 10
// 155.371 us; speedup vs baseline: 1.3004x; 1.3004x over previous
//
#include <hip/hip_runtime.h>
#include <hip/hip_bf16.h>

// Chamfer loss: preds/gts [8, 3, 8192] fp32 -> scalar fp32.
//
// Phase 0 (pack): refs in pair-SoA form: XY[p]=(xa,xb,ya,yb),
//                 ZW[p]=(za,zb,wa,wb), w=-0.5*|y|^2. Zeroes acc+cnt.
// Phase 1 (partial): per-query max_j(dot - 0.5*ry), refs LDS-staged
//                 (broadcast ds_read_b128, in-order lgkmcnt -> no SMEM
//                 serialization like r7's s_load regression). Inner loop:
//                 2 refs/instr via v_pk_fma_f32 (3 pk_fma + 1 v_max3 per
//                 query per ref-PAIR) = 2 VALU instr per (query,ref) pair.
// Phase 2 (reduce): min over splits, block sum, double atomic add; last
//                 block (atomic ticket) writes the float output.

typedef float f32x2 __attribute__((ext_vector_type(2)));
typedef float f32x4 __attribute__((ext_vector_type(4)));

#define CN 8192
#define NBATCH 8
#define BQ 2048        // queries per block
#define IPT 8          // queries per thread (256 threads * 8)
#define SPLITS 8       // ref-range splits
#define RB (CN / SPLITS)   // 1024 refs per block
#define QCHUNKS (CN / BQ)  // 4
#define NPAIR (CN / 2)     // 4096 ref-pairs per batch

__global__ __launch_bounds__(256) void chamfer_pack(
    const float* __restrict__ preds, const float* __restrict__ gts,
    f32x4* __restrict__ xyP, f32x4* __restrict__ zwP,
    f32x4* __restrict__ xyG, f32x4* __restrict__ zwG,
    double* __restrict__ acc, unsigned* __restrict__ cnt) {
  const int g = blockIdx.x * 256 + threadIdx.x;  // 65536 = 2 * 8 * 4096
  if (g == 0) { *acc = 0.0; *cnt = 0u; }
  const int tt  = g >> 15;             // 0: preds, 1: gts
  const int idx = g & 32767;
  const int b = idx >> 12, j = idx & (NPAIR - 1);
  const float* __restrict__ src = (tt ? gts : preds) + b * 3 * CN;
  const float2 vx = ((const float2*)(src))[j];          // points 2j, 2j+1
  const float2 vy = ((const float2*)(src + CN))[j];
  const float2 vz = ((const float2*)(src + 2 * CN))[j];
  const float w0 = -0.5f * fmaf(vx.x, vx.x, fmaf(vy.x, vy.x, vz.x * vz.x));
  const float w1 = -0.5f * fmaf(vx.y, vx.y, fmaf(vy.y, vy.y, vz.y * vz.y));
  f32x4* __restrict__ xy = tt ? xyG : xyP;
  f32x4* __restrict__ zw = tt ? zwG : zwP;
  xy[b * NPAIR + j] = (f32x4){vx.x, vx.y, vy.x, vy.y};
  zw[b * NPAIR + j] = (f32x4){vz.x, vz.y, w0, w1};
}

__global__ __launch_bounds__(256, 2) void chamfer_partial(
    const float* __restrict__ preds, const float* __restrict__ gts,
    const f32x4* __restrict__ xyP, const f32x4* __restrict__ zwP,
    const f32x4* __restrict__ xyG, const f32x4* __restrict__ zwG,
    float* __restrict__ partial) {
  const int bid = blockIdx.x;            // 512 blocks
  const int s     = bid & (SPLITS - 1);
  const int qc    = (bid >> 3) & (QCHUNKS - 1);
  const int batch = (bid >> 5) & (NBATCH - 1);
  const int dir   = bid >> 8;            // 0: queries=preds, 1: queries=gts

  const float* __restrict__ Q = (dir ? gts : preds) + batch * 3 * CN;
  // refs are the OTHER tensor's pair arrays
  const f32x4* __restrict__ XY =
      (dir ? xyP : xyG) + batch * NPAIR + s * (RB / 2);
  const f32x4* __restrict__ ZW =
      (dir ? zwP : zwG) + batch * NPAIR + s * (RB / 2);
  const int tid = threadIdx.x;

  __shared__ f32x4 lxy[RB / 2];   // 512 * 16B = 8KB
  __shared__ f32x4 lzw[RB / 2];   // 8KB
  lxy[tid]       = XY[tid];
  lxy[tid + 256] = XY[tid + 256];
  lzw[tid]       = ZW[tid];
  lzw[tid + 256] = ZW[tid + 256];

  // Queries: broadcast each coord into a float2 pair (loop-invariant).
  f32x2 bx[IPT], by[IPT], bz[IPT];
  float xw[IPT], mm[IPT];
#pragma unroll
  for (int k = 0; k < IPT; ++k) {
    const int q = qc * BQ + k * 256 + tid;
    const float a0 = Q[q], a1 = Q[CN + q], a2 = Q[2 * CN + q];
    bx[k] = (f32x2){a0, a0};
    by[k] = (f32x2){a1, a1};
    bz[k] = (f32x2){a2, a2};
    xw[k] = -0.5f * fmaf(a0, a0, fmaf(a1, a1, a2 * a2));
    mm[k] = -INFINITY;   // tracks max_j (dot - 0.5*ry)
  }
  __syncthreads();

#pragma unroll 4
  for (int p = 0; p < RB / 2; ++p) {
    const f32x4 xy = lxy[p];   // broadcast ds_read_b128, conflict-free
    const f32x4 zw = lzw[p];
    const f32x2 X2 = xy.lo, Y2 = xy.hi, Z2 = zw.lo, W2 = zw.hi;
#pragma unroll
    for (int k = 0; k < IPT; ++k) {
      f32x2 t;
      asm("v_pk_fma_f32 %0, %1, %2, %3"
          : "=v"(t) : "v"(bz[k]), "v"(Z2), "v"(W2));
      asm("v_pk_fma_f32 %0, %1, %2, %0"
          : "+v"(t) : "v"(by[k]), "v"(Y2));
      asm("v_pk_fma_f32 %0, %1, %2, %0"
          : "+v"(t) : "v"(bx[k]), "v"(X2));
      asm("v_max3_f32 %0, %0, %1, %2"
          : "+v"(mm[k]) : "v"(t.x), "v"(t.y));
    }
  }

  // partial = rx + min_j(ry - 2dot) = -2*(xw + mm)
  float* __restrict__ P =
      partial +
      (size_t)(((dir * NBATCH + batch) * QCHUNKS + qc) * SPLITS + s) * BQ;
#pragma unroll
  for (int k = 0; k < IPT; ++k) P[k * 256 + tid] = -2.0f * (xw[k] + mm[k]);
}

__global__ __launch_bounds__(256) void chamfer_reduce(
    const float* __restrict__ partial, double* __restrict__ acc,
    unsigned* __restrict__ cnt, float* __restrict__ out) {
  const int tid = threadIdx.x;
  const int g = blockIdx.x * 256 + tid;   // 131072 queries
  const int qlocal = g & (BQ - 1);
  const int grp = g >> 11;                // (dir*8+batch)*QCHUNKS+qc

  const float* __restrict__ P = partial + (size_t)grp * (SPLITS * BQ) + qlocal;
  float m = P[0];
#pragma unroll
  for (int s2 = 1; s2 < SPLITS; ++s2) m = fminf(m, P[s2 * BQ]);

  float v = m;
#pragma unroll
  for (int off = 32; off > 0; off >>= 1) v += __shfl_down(v, off, 64);

  __shared__ float wsum[4];
  if ((tid & 63) == 0) wsum[tid >> 6] = v;
  __syncthreads();
  if (tid == 0) {
    atomicAdd(acc, (double)(wsum[0] + wsum[1] + wsum[2] + wsum[3]));
    __threadfence();
    const unsigned t = atomicAdd(cnt, 1u);
    if (t == gridDim.x - 1) {
      const double total = atomicAdd(acc, 0.0);
      out[0] = (float)total;
    }
  }
}

extern "C" void kernel_launch(void* const* d_in, const int* in_sizes, int n_in,
                              void* d_out, int out_size, void* d_ws, size_t ws_size,
                              hipStream_t stream) {
  const float* preds = (const float*)d_in[0];
  const float* gts   = (const float*)d_in[1];

  double*   acc = (double*)d_ws;
  unsigned* cnt = (unsigned*)((char*)d_ws + 8);
  char* base = (char*)d_ws + 256;
  const size_t PAIRB = (size_t)NBATCH * NPAIR * 16;   // 512KB each
  f32x4* xyP = (f32x4*)(base);
  f32x4* zwP = (f32x4*)(base + PAIRB);
  f32x4* xyG = (f32x4*)(base + 2 * PAIRB);
  f32x4* zwG = (f32x4*)(base + 3 * PAIRB);
  float* partial = (float*)(base + 4 * PAIRB);        // 4MB

  chamfer_pack<<<256, 256, 0, stream>>>(preds, gts, xyP, zwP, xyG, zwG, acc, cnt);
  chamfer_partial<<<512, 256, 0, stream>>>(preds, gts, xyP, zwP, xyG, zwG, partial);
  chamfer_reduce<<<512, 256, 0, stream>>>(partial, acc, cnt, (float*)d_out);
}

// Round 11
// 153.189 us; speedup vs baseline: 1.3189x; 1.0142x over previous
//
#include <hip/hip_runtime.h>
#include <hip/hip_bf16.h>

// Chamfer loss: preds/gts [8, 3, 8192] fp32 -> scalar fp32.
//
// partial: each block owns (dir, batch, qchunk, split). It packs its 512-ref
//   slice into LDS pair-SoA (xy=(xa,xb,ya,yb), zw=(za,zb,wa,wb), w=-.5|y|^2),
//   then per query tracks max_j(dot - .5ry) with v_pk_fma_f32 (2 refs/instr):
//   3 pk_fma + 1 v_max3 per ref-PAIR per query = 2 VALU instr/pair.
//   IPT=16 queries/thread -> 64 VALU instr per 2 ds_read_b128 (VALU-bound;
//   r10's IPT=8 was LDS-bound at 61% VALUBusy). Rotating prefetch gives a
//   full-iteration (128 cyc) load-use distance.
// reduce: min over 16 splits, block sum, double atomic add; last block
//   (atomic ticket) writes the float output. acc/cnt zeroed via tiny memset.

typedef float f32x2 __attribute__((ext_vector_type(2)));
typedef float f32x4 __attribute__((ext_vector_type(4)));

#define CN 8192
#define NBATCH 8
#define BQ 4096        // queries per block
#define IPT 16         // queries per thread (256 threads * 16)
#define SPLITS 16      // ref-range splits
#define RB (CN / SPLITS)   // 512 refs per block
#define NP (RB / 2)        // 256 ref-pairs per block
#define QCHUNKS (CN / BQ)  // 2

__global__ __launch_bounds__(256) void chamfer_partial(
    const float* __restrict__ preds, const float* __restrict__ gts,
    float* __restrict__ partial) {
  const int bid = blockIdx.x;            // 512 blocks
  const int s     = bid & (SPLITS - 1);
  const int qc    = (bid >> 4) & (QCHUNKS - 1);
  const int batch = (bid >> 5) & (NBATCH - 1);
  const int dir   = bid >> 8;            // 0: queries=preds, 1: queries=gts

  const float* __restrict__ Q = (dir ? gts : preds) + batch * 3 * CN;
  const float* __restrict__ R = (dir ? preds : gts) + batch * 3 * CN;
  const int tid = threadIdx.x;

  // Stage + pack this block's 512-ref slice (256 pairs) into LDS.
  __shared__ f32x4 lxy[NP];   // 4KB: (xa,xb,ya,yb)
  __shared__ f32x4 lzw[NP];   // 4KB: (za,zb,wa,wb), w = -0.5*|y|^2
  {
    const int j = s * NP + tid;                       // float2 index in row
    const float2 vx = ((const float2*)R)[j];          // refs 2j, 2j+1
    const float2 vy = ((const float2*)(R + CN))[j];
    const float2 vz = ((const float2*)(R + 2 * CN))[j];
    const float w0 = -0.5f * fmaf(vx.x, vx.x, fmaf(vy.x, vy.x, vz.x * vz.x));
    const float w1 = -0.5f * fmaf(vx.y, vx.y, fmaf(vy.y, vy.y, vz.y * vz.y));
    lxy[tid] = (f32x4){vx.x, vx.y, vy.x, vy.y};
    lzw[tid] = (f32x4){vz.x, vz.y, w0, w1};
  }

  // Queries: broadcast each coord into a float2 pair (loop-invariant).
  f32x2 bx[IPT], by[IPT], bz[IPT];
  float xw[IPT], mm[IPT];
#pragma unroll
  for (int k = 0; k < IPT; ++k) {
    const int q = qc * BQ + k * 256 + tid;
    const float a0 = Q[q], a1 = Q[CN + q], a2 = Q[2 * CN + q];
    bx[k] = (f32x2){a0, a0};
    by[k] = (f32x2){a1, a1};
    bz[k] = (f32x2){a2, a2};
    xw[k] = -0.5f * fmaf(a0, a0, fmaf(a1, a1, a2 * a2));
    mm[k] = -INFINITY;   // tracks max_j (dot - 0.5*ry)
  }
  __syncthreads();

  // Rotating prefetch: loads for p+1 issued before compute of p.
  f32x4 xy = lxy[0], zw = lzw[0];
#pragma unroll 2
  for (int p = 0; p < NP; ++p) {
    const f32x4 nxy = lxy[(p + 1) & (NP - 1)];   // wrap read is harmless
    const f32x4 nzw = lzw[(p + 1) & (NP - 1)];
    const f32x2 X2 = xy.lo, Y2 = xy.hi, Z2 = zw.lo, W2 = zw.hi;
#pragma unroll
    for (int k = 0; k < IPT; ++k) {
      f32x2 t;
      asm("v_pk_fma_f32 %0, %1, %2, %3"
          : "=v"(t) : "v"(bz[k]), "v"(Z2), "v"(W2));
      asm("v_pk_fma_f32 %0, %1, %2, %0"
          : "+v"(t) : "v"(by[k]), "v"(Y2));
      asm("v_pk_fma_f32 %0, %1, %2, %0"
          : "+v"(t) : "v"(bx[k]), "v"(X2));
      asm("v_max3_f32 %0, %0, %1, %2"
          : "+v"(mm[k]) : "v"(t.x), "v"(t.y));
    }
    xy = nxy; zw = nzw;
  }

  // partial = rx + min_j(ry - 2dot) = -2*(xw + mm)
  float* __restrict__ P =
      partial +
      (size_t)(((dir * NBATCH + batch) * QCHUNKS + qc) * SPLITS + s) * BQ;
#pragma unroll
  for (int k = 0; k < IPT; ++k) P[k * 256 + tid] = -2.0f * (xw[k] + mm[k]);
}

__global__ __launch_bounds__(256) void chamfer_reduce(
    const float* __restrict__ partial, double* __restrict__ acc,
    unsigned* __restrict__ cnt, float* __restrict__ out) {
  const int tid = threadIdx.x;
  const int g = blockIdx.x * 256 + tid;   // 131072 queries
  const int qlocal = g & (BQ - 1);
  const int grp = g >> 12;                // (dir*8+batch)*QCHUNKS+qc, 0..31

  const float* __restrict__ P = partial + (size_t)grp * (SPLITS * BQ) + qlocal;
  float m = P[0];
#pragma unroll
  for (int s2 = 1; s2 < SPLITS; ++s2) m = fminf(m, P[s2 * BQ]);

  float v = m;
#pragma unroll
  for (int off = 32; off > 0; off >>= 1) v += __shfl_down(v, off, 64);

  __shared__ float wsum[4];
  if ((tid & 63) == 0) wsum[tid >> 6] = v;
  __syncthreads();
  if (tid == 0) {
    atomicAdd(acc, (double)(wsum[0] + wsum[1] + wsum[2] + wsum[3]));
    __threadfence();
    const unsigned t = atomicAdd(cnt, 1u);
    if (t == gridDim.x - 1) {
      const double total = atomicAdd(acc, 0.0);
      out[0] = (float)total;
    }
  }
}

extern "C" void kernel_launch(void* const* d_in, const int* in_sizes, int n_in,
                              void* d_out, int out_size, void* d_ws, size_t ws_size,
                              hipStream_t stream) {
  const float* preds = (const float*)d_in[0];
  const float* gts   = (const float*)d_in[1];

  double*   acc     = (double*)d_ws;
  unsigned* cnt     = (unsigned*)((char*)d_ws + 8);
  float*    partial = (float*)((char*)d_ws + 256);   // 8.4MB

  hipMemsetAsync(d_ws, 0, 12, stream);   // zero acc + cnt
  chamfer_partial<<<512, 256, 0, stream>>>(preds, gts, partial);
  chamfer_reduce<<<512, 256, 0, stream>>>(partial, acc, cnt, (float*)d_out);
}